// Round 1
// baseline (346.429 us; speedup 1.0000x reference)
//
#include <hip/hip_runtime.h>
#include <math.h>

// MarginLoss: out[b] = -relu(logits[b][label[b]] - max_{c != label[b]} logits[b][c])
// B=65536, C=1000, fp32. Memory-bound row reduction: one wave per row.

__global__ __launch_bounds__(256) void margin_loss_kernel(
    const float* __restrict__ logits,
    const int* __restrict__ label,
    float* __restrict__ out,
    int B, int C)
{
    const int wave = (blockIdx.x * blockDim.x + threadIdx.x) >> 6;  // global wave id = row
    const int lane = threadIdx.x & 63;
    if (wave >= B) return;

    const int lab = label[wave];
    const float4* __restrict__ row = (const float4*)(logits + (size_t)wave * (size_t)C);
    const int nvec = C >> 2;  // 250 float4 per row (C=1000 divisible by 4)

    float m  = -INFINITY;  // max over non-label classes (this lane's slice)
    float lv = -INFINITY;  // logit at label (only one lane sees it)

    for (int i = lane; i < nvec; i += 64) {
        float4 v = row[i];
        const int d = lab - (i << 2);
        if ((unsigned)d < 4u) {
            // label falls inside this float4: record it, mask to -inf for the max
            if (d == 0)      { lv = v.x; v.x = -INFINITY; }
            else if (d == 1) { lv = v.y; v.y = -INFINITY; }
            else if (d == 2) { lv = v.z; v.z = -INFINITY; }
            else             { lv = v.w; v.w = -INFINITY; }
        }
        m = fmaxf(m, fmaxf(fmaxf(v.x, v.y), fmaxf(v.z, v.w)));
    }

    // 64-lane butterfly reduction (wave = 64 on gfx950)
    #pragma unroll
    for (int off = 32; off > 0; off >>= 1) {
        m  = fmaxf(m,  __shfl_xor(m,  off));
        lv = fmaxf(lv, __shfl_xor(lv, off));
    }

    if (lane == 0) {
        const float diff = lv - m;
        out[wave] = -fmaxf(diff, 0.0f);   // MARGIN = 0
    }
}

extern "C" void kernel_launch(void* const* d_in, const int* in_sizes, int n_in,
                              void* d_out, int out_size, void* d_ws, size_t ws_size,
                              hipStream_t stream)
{
    const float* logits = (const float*)d_in[0];
    const int*   label  = (const int*)d_in[1];
    float*       out    = (float*)d_out;

    const int B = out_size;            // 65536
    const int C = in_sizes[0] / B;     // 1000

    // One wave per row; 4 waves (rows) per 256-thread block.
    const int rows_per_block = 256 / 64;
    const int grid = (B + rows_per_block - 1) / rows_per_block;
    margin_loss_kernel<<<grid, 256, 0, stream>>>(logits, label, out, B, C);
}

// Round 2
// 345.435 us; speedup vs baseline: 1.0029x; 1.0029x over previous
//
#include <hip/hip_runtime.h>
#include <math.h>

// MarginLoss: out[b] = -relu(logits[b][label[b]] - max_{c != label[b]} logits[b][c])
// B=65536, C=1000 fp32. Memory-bound (262 MB read / launch).
// One wave per row; all 4 float4 loads issued up front for MLP (4 outstanding
// global_load_dwordx4 per lane), branchless label masking, 6-step butterfly.

__global__ __launch_bounds__(256) void margin_loss_kernel(
    const float* __restrict__ logits,
    const int* __restrict__ label,
    float* __restrict__ out,
    int B)
{
    constexpr int NV = 250;  // 1000 / 4 float4 per row
    const int wave = (blockIdx.x * blockDim.x + threadIdx.x) >> 6;  // row
    const int lane = threadIdx.x & 63;
    if (wave >= B) return;

    const int lab = label[wave];
    const float4* __restrict__ row = (const float4*)(logits + (size_t)wave * 1000);

    // Issue all loads before any use: 4 loads in flight per lane.
    const int i0 = lane, i1 = lane + 64, i2 = lane + 128, i3 = lane + 192;
    float4 v0 = row[i0];
    float4 v1 = row[i1];
    float4 v2 = row[i2];
    float4 v3;
    if (i3 < NV) {
        v3 = row[i3];
    } else {
        v3 = make_float4(-INFINITY, -INFINITY, -INFINITY, -INFINITY);
    }

    float m  = -INFINITY;  // max over non-label elements in this lane's slice
    float lv = -INFINITY;  // label's logit (only the owning lane sets it)

    auto proc = [&](float4 v, int i) {
        const int d = lab - (i << 2);
        if ((unsigned)d < 4u) {   // compiles to cndmask selects, no branch needed
            lv = (d == 0) ? v.x : (d == 1) ? v.y : (d == 2) ? v.z : v.w;
            if (d == 0)      v.x = -INFINITY;
            else if (d == 1) v.y = -INFINITY;
            else if (d == 2) v.z = -INFINITY;
            else             v.w = -INFINITY;
        }
        m = fmaxf(m, fmaxf(fmaxf(v.x, v.y), fmaxf(v.z, v.w)));
    };
    // For lanes 58..63, i3 >= 250 -> d = lab - 4*i3 < 0 -> mask path skipped,
    // and v3 is -inf, so unconditional proc is safe.
    proc(v0, i0);
    proc(v1, i1);
    proc(v2, i2);
    proc(v3, i3);

    // Label value lives on exactly one lane: broadcast with a single shuffle.
    const int owner = (lab >> 2) & 63;
    const float lvs = __shfl(lv, owner);

    // 64-lane butterfly max-reduction for max_other.
    #pragma unroll
    for (int off = 32; off > 0; off >>= 1) {
        m = fmaxf(m, __shfl_xor(m, off));
    }

    if (lane == 0) {
        out[wave] = -fmaxf(lvs - m, 0.0f);  // MARGIN = 0
    }
}

extern "C" void kernel_launch(void* const* d_in, const int* in_sizes, int n_in,
                              void* d_out, int out_size, void* d_ws, size_t ws_size,
                              hipStream_t stream)
{
    const float* logits = (const float*)d_in[0];
    const int*   label  = (const int*)d_in[1];
    float*       out    = (float*)d_out;

    const int B = out_size;  // 65536

    const int rows_per_block = 256 / 64;  // 4 waves per block, 1 row per wave
    const int grid = (B + rows_per_block - 1) / rows_per_block;
    margin_loss_kernel<<<grid, 256, 0, stream>>>(logits, label, out, B);
}

// Round 3
// 320.282 us; speedup vs baseline: 1.0816x; 1.0785x over previous
//
#include <hip/hip_runtime.h>
#include <math.h>

// MarginLoss: out[b] = -relu(logits[b][label[b]] - max_{c != label[b]} logits[b][c])
// B=65536, C=1000 fp32. Pure streaming row-reduction, 262 MB read/launch.
// Persistent waves: 8192 waves, 8 rows each, 2-stage software pipeline so the
// next row's 4x global_load_dwordx4 (nontemporal) are in flight while the
// current row is reduced. One wave per row-slice, 64-lane butterfly max.

typedef float v4 __attribute__((ext_vector_type(4)));

constexpr int C  = 1000;
constexpr int NV = 250;  // float4 per row

__device__ __forceinline__ void load_row(const v4* __restrict__ p, int lane,
                                         v4& a, v4& b, v4& c, v4& d) {
    a = __builtin_nontemporal_load(p + lane);
    b = __builtin_nontemporal_load(p + lane + 64);
    c = __builtin_nontemporal_load(p + lane + 128);
    if (lane + 192 < NV) {                       // lanes 0..57
        d = __builtin_nontemporal_load(p + lane + 192);
    } else {
        d = (v4){-INFINITY, -INFINITY, -INFINITY, -INFINITY};
    }
}

__device__ __forceinline__ float row_result(v4 a, v4 b, v4 c, v4 d,
                                            int lane, int lab) {
    float m  = -INFINITY;   // max over non-label elements (this lane's slice)
    float lv = -INFINITY;   // label's logit (only the owning lane sets it)
    auto proc = [&](v4 v, int i) {
        const int dd = lab - (i << 2);
        if ((unsigned)dd < 4u) {   // cndmask selects
            lv = (dd == 0) ? v[0] : (dd == 1) ? v[1] : (dd == 2) ? v[2] : v[3];
            if (dd == 0)      v[0] = -INFINITY;
            else if (dd == 1) v[1] = -INFINITY;
            else if (dd == 2) v[2] = -INFINITY;
            else              v[3] = -INFINITY;
        }
        m = fmaxf(m, fmaxf(fmaxf(v[0], v[1]), fmaxf(v[2], v[3])));
    };
    // Tail lanes (i=lane+192 >= 250): dd < 0 so no label hit, and d == -inf.
    proc(a, lane); proc(b, lane + 64); proc(c, lane + 128); proc(d, lane + 192);

    const float lvs = __shfl(lv, (lab >> 2) & 63);  // broadcast from owner lane
    #pragma unroll
    for (int off = 32; off > 0; off >>= 1)
        m = fmaxf(m, __shfl_xor(m, off));
    return -fmaxf(lvs - m, 0.0f);  // MARGIN = 0
}

__global__ __launch_bounds__(256) void margin_loss_kernel(
    const float* __restrict__ logits,
    const int* __restrict__ label,
    float* __restrict__ out,
    int B, int nwaves)
{
    const int gwave = (blockIdx.x * blockDim.x + threadIdx.x) >> 6;
    const int lane  = threadIdx.x & 63;

    int r = gwave;
    if (r >= B) return;

    // Prologue: issue row r's loads.
    v4 a, b, c, d;
    load_row((const v4*)(logits + (size_t)r * C), lane, a, b, c, d);
    int lab = label[r];

    while (true) {
        const int rn = r + nwaves;
        v4 an, bn, cn, dn;
        int labn = 0;
        if (rn < B) {
            // Issue next row's loads BEFORE reducing the current row:
            // latency overlaps the reduction below.
            load_row((const v4*)(logits + (size_t)rn * C), lane, an, bn, cn, dn);
            labn = label[rn];
        }

        const float res = row_result(a, b, c, d, lane, lab);
        if (lane == 0) out[r] = res;

        if (rn >= B) break;
        a = an; b = bn; c = cn; d = dn; lab = labn;
        r = rn;
    }
}

extern "C" void kernel_launch(void* const* d_in, const int* in_sizes, int n_in,
                              void* d_out, int out_size, void* d_ws, size_t ws_size,
                              hipStream_t stream)
{
    const float* logits = (const float*)d_in[0];
    const int*   label  = (const int*)d_in[1];
    float*       out    = (float*)d_out;

    const int B = out_size;  // 65536

    // Persistent waves: 8192 waves (2048 blocks x 4 waves) -> 8 rows per wave.
    int nwaves = 8192;
    if (nwaves > B) nwaves = B;
    const int rows_per_block = 256 / 64;
    const int grid = (nwaves + rows_per_block - 1) / rows_per_block;
    margin_loss_kernel<<<grid, 256, 0, stream>>>(logits, label, out, B, nwaves);
}